// Round 3
// baseline (72.376 us; speedup 1.0000x reference)
//
#include <hip/hip_runtime.h>
#include <math.h>

// DiffractiveLayer: out[j] = sum_i modes[i]*G[i,j]*dA, G[i,j] = f(a-c, b-d)
// -> 2D complex convolution with a 191x191 tap table.
//
// Structure (R4): TWO dispatches only.
//   1. precompute: taps (fp64 geometry + arg-reduced hw sincos) + modes
//      + zero d_out (replaces a separate memset dispatch).
//   2. conv: register-blocked direct convolution out of LDS, atomicAdd
//      accumulation into d_out.
// R3's single-kernel + device-scope spin-barrier variant measured 241 us:
// cross-XCD coherence storms make grid barriers ~100x the cost of the
// launch gaps they save. Never again on this chip.
//
// R5: v_pk_fma_f32 inner loop (op_sel/neg_lo encode complex swizzle).
// Measured -6.1 us -> CDNA4 packed fp32 is dual-rate (like CDNA2).
// R6: 16 source rows/block, 8 outputs/thread via TWO 4-wide windows.
// FAILED: modes staging only covered half of each row (24 float4 of 48).
// R7: fix = 4 staging iters/thread (idx/48, idx%48). Window math was
// verified correct in R6 post-mortem (window1 bit-identical to R5
// q=0..11; window2 gb2=22-2q matches base 92-4(q+12)).
// Conv pk-issue floor: 48*16*2cyc * 3456 waves / 1024 SIMD = 2.16 us.
//
// Timed-iteration floor: harness poisons 268 MB of d_ws every iteration
// (~40 us at ~84% HBM peak) + ~10 restore dispatches of graph replay.
// Our dispatches are ~5-6 us combined.

#define NN 96
#define M (NN*NN)
#define GH 191           // 2N-1 tap rows/cols
#define GWG 192          // global tap row stride (float2)
#define GW2 200          // LDS tap row stride (float2), slack for ring overrun
#define MW2 104          // LDS modes row stride (float2), de-banked

typedef __attribute__((ext_vector_type(4))) float f32x4;
typedef __attribute__((ext_vector_type(2))) float f32x2;

__device__ float2 g_G[GH * GWG];    // tap table, dA folded in
__device__ float2 g_modes[M];       // exp(j*w)*x

__global__ __launch_bounds__(256) void precompute_kernel(
    const float* __restrict__ x, const float* __restrict__ w,
    const float* __restrict__ xc, const float* __restrict__ yc,
    float* __restrict__ out, int out_floats) {
  const double DZ = 1e-5, LAMBDA = 1.55e-6;
  const double TWO_PI     = 6.283185307179586476925;
  const double INV_TWO_PI = 0.15915494309189533577;
  const double K  = TWO_PI / LAMBDA;
  const double DA = LAMBDA * LAMBDA;          // pitch == lambda

  int idx = blockIdx.x * 256 + threadIdx.x;

  if (idx < out_floats) out[idx] = 0.f;       // fused d_out zeroing

  if (idx < GH * GH) {
    int u = idx / GH - (NN - 1);
    int v = idx % GH - (NN - 1);
    // fp32-rounded input coords match the reference's systematic rounding
    double dx = (double)xc[u < 0 ? -u : u] - (double)xc[0];
    double dy = (double)yc[v < 0 ? -v : v] - (double)yc[0];
    double r2 = dx * dx + dy * dy + DZ * DZ;
    double r  = sqrt(r2);
    double invr2 = 1.0 / r2;
    double amp = DZ * DA * invr2;               // dz/r^2 * dA
    double A = amp * INV_TWO_PI * (r * invr2);  // amp/(2*pi*r)
    double B = amp / LAMBDA;
    double ph = K * r;                          // up to ~843 rad
    double nred = rint(ph * INV_TWO_PI);
    float red = (float)fma(-nred, TWO_PI, ph);  // |red| <= pi, err ~1e-13
    float s, cs;
    __sincosf(red, &s, &cs);
    // (A - jB)(cs + js) = (A cs + B s) + j(A s - B cs)
    g_G[(u + NN - 1) * GWG + (v + NN - 1)] =
        make_float2((float)(A * cs + B * s), (float)(A * s - B * cs));
  } else if (idx < GH * GH + M) {
    int i = idx - GH * GH;
    float s, cs;
    sincosf(w[i], &s, &cs);
    float xv = x[i];
    g_modes[i] = make_float2(cs * xv, s * xv);
  }
}

// grid: (96 output rows c, 6 source-row chunks of 16), block 192.
// Thread t: q = t%12 -> outputs d = 4q..4q+3 AND 48+4q..51+4q;
//           h = t/12 -> source row a0+h (16 rows/block).
// Two register rings of 3 float4 each -> 2 new b128 tap reads per 2 b-steps
// feeding 16 complex MACs (32 v_pk_fma_f32).
__global__ __launch_bounds__(192) void conv_kernel(float* __restrict__ out,
                                                   int interleaved) {
  int c  = blockIdx.x;
  int a0 = blockIdx.y * 16;
  int t  = threadIdx.x;

  __shared__ float2 s_modes[16 * MW2];      // 16 rows x 96 (stride 104)
  __shared__ float2 s_G[16 * GW2 + 8];      // 16 rows x 192 (stride 200) + slack
  __shared__ float2 s_red[16 * NN];

  // stage modes: 16 rows x 48 float4, 4 per thread
  #pragma unroll
  for (int k = 0; k < 4; ++k) {
    int idx = k * 192 + t;              // 0..767
    int row = idx / 48, col = idx % 48;
    const float4* src = (const float4*)(g_modes + (a0 + row) * NN);
    ((float4*)(s_modes + row * MW2))[col] = src[col];
  }
  // stage taps: 16 rows x 96 float4, 8 per thread
  #pragma unroll
  for (int k = 0; k < 8; ++k) {
    int idx = k * 192 + t;              // 0..1535
    int row = idx / 96, col = idx % 96;
    const float4* src = (const float4*)(g_G + (a0 + row - c + (NN - 1)) * GWG);
    ((float4*)(s_G + row * GW2))[col] = src[col];
  }
  __syncthreads();

  int q = t % 12;
  int h = t / 12;
  const f32x4* Grow = (const f32x4*)(s_G + h * GW2);
  const f32x4* Mrow = (const f32x4*)(s_modes + h * MW2);
  int gb1 = 46 - 2 * q;                 // window1: outputs 4q..4q+3
  int gb2 = 22 - 2 * q;                 // window2: outputs 48+4q..51+4q

  f32x4 p0 = Grow[gb1];
  f32x4 p1 = Grow[gb1 + 1];
  f32x4 p2 = Grow[gb1 + 2];
  f32x4 r0 = Grow[gb2];
  f32x4 r1 = Grow[gb2 + 1];
  f32x4 r2 = Grow[gb2 + 2];
  f32x2 a0c = {0.f, 0.f}, a1c = {0.f, 0.f}, a2c = {0.f, 0.f}, a3c = {0.f, 0.f};
  f32x2 b0c = {0.f, 0.f}, b1c = {0.f, 0.f}, b2c = {0.f, 0.f}, b3c = {0.f, 0.f};

#define LO2(v4) __builtin_shufflevector(v4, v4, 0, 1)
#define HI2(v4) __builtin_shufflevector(v4, v4, 2, 3)

// Complex MAC  acc += m * g  with m=(mr,mi), g=(gr,gi), all f32x2 pairs.
// inst1: lo: mr*gr + acc.x            hi: mr*gi + acc.y
// inst2: lo: mi*(-gi) + acc.x         hi: mi*gr + acc.y
// -> identical per-component FLOP order to the scalar 4-fma version.
#define CFMA_PK(acc, m2, gg)                                                  \
  asm("v_pk_fma_f32 %0, %1, %2, %0 op_sel:[0,0,0] op_sel_hi:[0,1,1]\n\t"      \
      "v_pk_fma_f32 %0, %1, %2, %0 op_sel:[1,1,0] op_sel_hi:[1,0,1] neg_lo:[0,1,0]" \
      : "+v"(acc) : "v"(m2), "v"(gg))

  #pragma unroll 6
  for (int b = 0; b < NN; b += 2) {
    f32x4 mm = Mrow[b >> 1];   // m[b]=(x,y)  m[b+1]=(z,w)
    f32x2 m01 = LO2(mm), m23 = HI2(mm);
    {
      f32x2 p0a = LO2(p0), p0b = HI2(p0);
      f32x2 p1a = LO2(p1), p1b = HI2(p1);
      f32x2 p2a = LO2(p2);
      CFMA_PK(a0c, m01, p1b);
      CFMA_PK(a0c, m23, p2a);
      CFMA_PK(a1c, m01, p1a);
      CFMA_PK(a1c, m23, p1b);
      CFMA_PK(a2c, m01, p0b);
      CFMA_PK(a2c, m23, p1a);
      CFMA_PK(a3c, m01, p0a);
      CFMA_PK(a3c, m23, p0b);
    }
    {
      f32x2 r0a = LO2(r0), r0b = HI2(r0);
      f32x2 r1a = LO2(r1), r1b = HI2(r1);
      f32x2 r2a = LO2(r2);
      CFMA_PK(b0c, m01, r1b);
      CFMA_PK(b0c, m23, r2a);
      CFMA_PK(b1c, m01, r1a);
      CFMA_PK(b1c, m23, r1b);
      CFMA_PK(b2c, m01, r0b);
      CFMA_PK(b2c, m23, r1a);
      CFMA_PK(b3c, m01, r0a);
      CFMA_PK(b3c, m23, r0b);
    }
    p0 = p1; p1 = p2; p2 = Grow[gb1 + 3 + (b >> 1)];   // slack covers overrun
    r0 = r1; r1 = r2; r2 = Grow[gb2 + 3 + (b >> 1)];
  }
#undef CFMA_PK
#undef LO2
#undef HI2

  int d1 = 4 * q;
  int d2 = 48 + 4 * q;
  s_red[h * NN + d1 + 0] = make_float2(a0c.x, a0c.y);
  s_red[h * NN + d1 + 1] = make_float2(a1c.x, a1c.y);
  s_red[h * NN + d1 + 2] = make_float2(a2c.x, a2c.y);
  s_red[h * NN + d1 + 3] = make_float2(a3c.x, a3c.y);
  s_red[h * NN + d2 + 0] = make_float2(b0c.x, b0c.y);
  s_red[h * NN + d2 + 1] = make_float2(b1c.x, b1c.y);
  s_red[h * NN + d2 + 2] = make_float2(b2c.x, b2c.y);
  s_red[h * NN + d2 + 3] = make_float2(b3c.x, b3c.y);
  __syncthreads();

  if (t < NN) {
    float re = 0.f, im = 0.f;
    #pragma unroll
    for (int hh = 0; hh < 16; ++hh) {
      re += s_red[hh * NN + t].x;
      im += s_red[hh * NN + t].y;
    }
    int j = c * NN + t;
    if (interleaved) {
      atomicAdd(out + 2 * j,     re);
      atomicAdd(out + 2 * j + 1, im);
    } else {
      atomicAdd(out + j, re);
    }
  }
}

extern "C" void kernel_launch(void* const* d_in, const int* in_sizes, int n_in,
                              void* d_out, int out_size, void* d_ws, size_t ws_size,
                              hipStream_t stream) {
  const float* x  = (const float*)d_in[0];
  const float* w  = (const float*)d_in[1];
  const float* xc = (const float*)d_in[2];
  const float* yc = (const float*)d_in[3];
  float* out = (float*)d_out;

  int interleaved = (out_size >= 2 * M) ? 1 : 0;
  int out_floats  = interleaved ? 2 * M : M;

  int total = GH * GH + M;   // 45697 work items; out_floats < total covered
  precompute_kernel<<<(total + 255) / 256, 256, 0, stream>>>(
      x, w, xc, yc, out, out_floats);

  conv_kernel<<<dim3(NN, 6), 192, 0, stream>>>(out, interleaved);
}

// Round 4
// 68.909 us; speedup vs baseline: 1.0503x; 1.0503x over previous
//
#include <hip/hip_runtime.h>
#include <math.h>

// DiffractiveLayer: out[j] = sum_i modes[i]*G[i,j]*dA, G[i,j] = f(a-c, b-d)
// -> 2D complex convolution with a 191x191 tap table.
//
// Structure: TWO dispatches.
//   1. precompute: taps (fp64 geometry + arg-reduced hw sincos) + modes
//      + zero d_out.
//   2. conv: register-blocked direct convolution out of LDS, atomicAdd
//      accumulation into d_out.
// R3: grid-wide spin barrier = 241 us (cross-XCD coherence storm). Never.
// R5: v_pk_fma_f32 inner loop -> CDNA4 packed fp32 is dual-rate. 68.86 us.
// R6/R7: 16 rows/block, 8 outputs/thread: 72.4 us REGRESSION. Halved wave
//   count (1.7/SIMD) + 2.25 blocks/CU imbalance -> latency exposed.
//   Lesson: occupancy >= ~3.4 waves/SIMD beats per-cmac overhead savings.
// R8 (this): R5 per-thread structure EXACTLY, but each block does half the
//   b-range. Grid (96,12,2) = 2304 blocks = 9.00/CU (zero tail), 6.75
//   waves/SIMD. LDS trimmed to ~13 KiB (76-f4 tap window, 24-f4 modes,
//   s_red aliased onto s_G after a barrier) -> all 9 resident.
//   Per-step FLOP order identical to R5; only b-chunk reassociation.
//
// Timed-iteration floor: harness poisons 268 MB of d_ws every iteration
// (~40 us at ~84% HBM peak) + ~20 us replay/restore. Ours ~5 us.

#define NN 96
#define M (NN*NN)
#define GH 191           // 2N-1 tap rows/cols
#define GWG 192          // global tap row stride (float2)
#define GW4 76           // LDS tap row stride (float4): 73 used + ring slack
#define MW4 26           // LDS modes row stride (float4): 24 used + pad

typedef __attribute__((ext_vector_type(4))) float f32x4;
typedef __attribute__((ext_vector_type(2))) float f32x2;

__device__ __attribute__((aligned(16))) float2 g_G[GH * GWG];  // taps, dA folded
__device__ __attribute__((aligned(16))) float2 g_modes[M];     // exp(j*w)*x

__global__ __launch_bounds__(256) void precompute_kernel(
    const float* __restrict__ x, const float* __restrict__ w,
    const float* __restrict__ xc, const float* __restrict__ yc,
    float* __restrict__ out, int out_floats) {
  const double DZ = 1e-5, LAMBDA = 1.55e-6;
  const double TWO_PI     = 6.283185307179586476925;
  const double INV_TWO_PI = 0.15915494309189533577;
  const double K  = TWO_PI / LAMBDA;
  const double DA = LAMBDA * LAMBDA;          // pitch == lambda

  int idx = blockIdx.x * 256 + threadIdx.x;

  if (idx < out_floats) out[idx] = 0.f;       // fused d_out zeroing

  if (idx < GH * GH) {
    int u = idx / GH - (NN - 1);
    int v = idx % GH - (NN - 1);
    // fp32-rounded input coords match the reference's systematic rounding
    double dx = (double)xc[u < 0 ? -u : u] - (double)xc[0];
    double dy = (double)yc[v < 0 ? -v : v] - (double)yc[0];
    double r2 = dx * dx + dy * dy + DZ * DZ;
    double r  = sqrt(r2);
    double invr2 = 1.0 / r2;
    double amp = DZ * DA * invr2;               // dz/r^2 * dA
    double A = amp * INV_TWO_PI * (r * invr2);  // amp/(2*pi*r)
    double B = amp / LAMBDA;
    double ph = K * r;                          // up to ~843 rad
    double nred = rint(ph * INV_TWO_PI);
    float red = (float)fma(-nred, TWO_PI, ph);  // |red| <= pi, err ~1e-13
    float s, cs;
    __sincosf(red, &s, &cs);
    // (A - jB)(cs + js) = (A cs + B s) + j(A s - B cs)
    g_G[(u + NN - 1) * GWG + (v + NN - 1)] =
        make_float2((float)(A * cs + B * s), (float)(A * s - B * cs));
  } else if (idx < GH * GH + M) {
    int i = idx - GH * GH;
    float s, cs;
    sincosf(w[i], &s, &cs);
    float xv = x[i];
    g_modes[i] = make_float2(cs * xv, s * xv);
  }
}

// grid: (96 output rows c, 12 source-row chunks of 8, 2 b-halves), block 192.
// Thread t: q = t%24 -> outputs d = 4q..4q+3; h = t/24 -> source row a0+h.
// b-range: [48*bh, 48*bh+95..] -> 24 inner steps of 2 columns.
// Register ring of 3 float4 -> 1 new b128 tap read per step (2 b-cols).
__global__ __launch_bounds__(192) void conv_kernel(float* __restrict__ out,
                                                   int interleaved) {
  int c  = blockIdx.x;
  int a0 = blockIdx.y * 8;
  int bh = blockIdx.z;                  // b-half: columns 48*bh .. 48*bh+47
  int t  = threadIdx.x;

  __shared__ f32x4 s_G4[8 * GW4];       // 8 rows x 76 float4 (9728 B)
  __shared__ f32x4 s_m4[8 * MW4];       // 8 rows x 26 float4 (3328 B)
  float2* s_red = (float2*)s_G4;        // aliased AFTER barrier (768 f2 fits)

  const f32x4* gG4 = (const f32x4*)g_G;       // 18336 float4 total
  const f32x4* gm4 = (const f32x4*)g_modes;   // 48 float4 per mode row

  // stage modes: 8 rows x 24 float4 = 192 -> exactly 1 per thread
  {
    int row = t / 24, col = t % 24;
    s_m4[row * MW4 + col] = gm4[(a0 + row) * 48 + 24 * bh + col];
  }
  // stage taps: 8 rows x 76 float4 = 608 of 768 slots
  #pragma unroll
  for (int k = 0; k < 4; ++k) {
    int idx = k * 192 + t;
    if (idx < 8 * GW4) {
      int row = idx / GW4, col = idx % GW4;
      int grow = a0 + row - c + (NN - 1);       // 0..190
      int gidx = grow * 96 + 24 * bh + col;     // col 73..75 unused slack
      if (gidx > GH * 96 - 1) gidx = GH * 96 - 1;   // clamp corner (unused)
      s_G4[row * GW4 + col] = gG4[gidx];
    }
  }
  __syncthreads();

  int q = t % 24;
  int h = t / 24;
  const f32x4* Grow = s_G4 + h * GW4;
  const f32x4* Mrow = s_m4 + h * MW4;
  int gb = 46 - 2 * q;                  // window base (local f4 index)

  f32x4 g0 = Grow[gb];
  f32x4 g1 = Grow[gb + 1];
  f32x4 g2 = Grow[gb + 2];
  f32x2 a0c = {0.f, 0.f}, a1c = {0.f, 0.f}, a2c = {0.f, 0.f}, a3c = {0.f, 0.f};

#define LO2(v4) __builtin_shufflevector(v4, v4, 0, 1)
#define HI2(v4) __builtin_shufflevector(v4, v4, 2, 3)

// Complex MAC  acc += m * g  with m=(mr,mi), g=(gr,gi), all f32x2 pairs.
// inst1: lo: mr*gr + acc.x            hi: mr*gi + acc.y
// inst2: lo: mi*(-gi) + acc.x         hi: mi*gr + acc.y
#define CFMA_PK(acc, m2, gg)                                                  \
  asm("v_pk_fma_f32 %0, %1, %2, %0 op_sel:[0,0,0] op_sel_hi:[0,1,1]\n\t"      \
      "v_pk_fma_f32 %0, %1, %2, %0 op_sel:[1,1,0] op_sel_hi:[1,0,1] neg_lo:[0,1,0]" \
      : "+v"(acc) : "v"(m2), "v"(gg))

  #pragma unroll 6
  for (int s = 0; s < 24; ++s) {        // 24 steps x 2 b-columns
    f32x4 mm = Mrow[s];                 // m[2s]=(x,y)  m[2s+1]=(z,w)
    f32x2 m01 = LO2(mm), m23 = HI2(mm);
    f32x2 g0a = LO2(g0), g0b = HI2(g0);
    f32x2 g1a = LO2(g1), g1b = HI2(g1);
    f32x2 g2a = LO2(g2);
    CFMA_PK(a0c, m01, g1b);
    CFMA_PK(a0c, m23, g2a);
    CFMA_PK(a1c, m01, g1a);
    CFMA_PK(a1c, m23, g1b);
    CFMA_PK(a2c, m01, g0b);
    CFMA_PK(a2c, m23, g1a);
    CFMA_PK(a3c, m01, g0a);
    CFMA_PK(a3c, m23, g0b);
    g0 = g1;
    g1 = g2;
    g2 = Grow[gb + 3 + s];              // max 72 < GW4; final read discarded
  }
#undef CFMA_PK
#undef LO2
#undef HI2

  __syncthreads();                      // s_G4 dead -> reuse as s_red

  int dbase = 4 * q;
  s_red[h * NN + dbase + 0] = make_float2(a0c.x, a0c.y);
  s_red[h * NN + dbase + 1] = make_float2(a1c.x, a1c.y);
  s_red[h * NN + dbase + 2] = make_float2(a2c.x, a2c.y);
  s_red[h * NN + dbase + 3] = make_float2(a3c.x, a3c.y);
  __syncthreads();

  if (t < NN) {
    float re = 0.f, im = 0.f;
    #pragma unroll
    for (int hh = 0; hh < 8; ++hh) {
      re += s_red[hh * NN + t].x;
      im += s_red[hh * NN + t].y;
    }
    int j = c * NN + t;
    if (interleaved) {
      atomicAdd(out + 2 * j,     re);
      atomicAdd(out + 2 * j + 1, im);
    } else {
      atomicAdd(out + j, re);
    }
  }
}

extern "C" void kernel_launch(void* const* d_in, const int* in_sizes, int n_in,
                              void* d_out, int out_size, void* d_ws, size_t ws_size,
                              hipStream_t stream) {
  const float* x  = (const float*)d_in[0];
  const float* w  = (const float*)d_in[1];
  const float* xc = (const float*)d_in[2];
  const float* yc = (const float*)d_in[3];
  float* out = (float*)d_out;

  int interleaved = (out_size >= 2 * M) ? 1 : 0;
  int out_floats  = interleaved ? 2 * M : M;

  int total = GH * GH + M;   // 45697 work items; out_floats < total covered
  precompute_kernel<<<(total + 255) / 256, 256, 0, stream>>>(
      x, w, xc, yc, out, out_floats);

  conv_kernel<<<dim3(NN, 12, 2), 192, 0, stream>>>(out, interleaved);
}